// Round 1
// baseline (585.449 us; speedup 1.0000x reference)
//
#include <hip/hip_runtime.h>
#include <hip/hip_bf16.h>
#include <hip/hip_fp16.h>

typedef _Float16 f16x8 __attribute__((ext_vector_type(8)));
typedef float    f32x4 __attribute__((ext_vector_type(4)));

#define MFMA16(a, b, c) __builtin_amdgcn_mfma_f32_16x16x32_f16(a, b, c, 0, 0, 0)

static constexpr int BN   = 8;     // batch
static constexpr int CIN  = 512;   // channels
static constexpr int NHW  = 4096;  // H*W
static constexpr int OD   = 256;   // INTER

__device__ __forceinline__ f16x8 cvt8(const float4 a, const float4 b) {
    f16x8 r;
    r[0] = (_Float16)a.x; r[1] = (_Float16)a.y; r[2] = (_Float16)a.z; r[3] = (_Float16)a.w;
    r[4] = (_Float16)b.x; r[5] = (_Float16)b.y; r[6] = (_Float16)b.z; r[7] = (_Float16)b.w;
    return r;
}

// ---------------------------------------------------------------------------
// Prep: T[b][n][o] = sum_c x[b][c][n] * w[o][c] + bias[o], stored as f16.
// sel=0 -> theta (x_query)  -> Qws ;  sel=1 -> phi (x_support) -> Kws
// grid: (64 n-tiles, 4 o-tiles, 16 = b*2+sel), block 256
// ---------------------------------------------------------------------------
__global__ __launch_bounds__(256)
void prep_gemm(const float* __restrict__ xq, const float* __restrict__ xs,
               const float* __restrict__ thw, const float* __restrict__ thb,
               const float* __restrict__ phw, const float* __restrict__ phb,
               _Float16* __restrict__ Qws, _Float16* __restrict__ Kws)
{
    const int nt = blockIdx.x, ot = blockIdx.y, z = blockIdx.z;
    const int b = z >> 1, sel = z & 1;
    const float* x    = (sel ? xs : xq) + (size_t)b * CIN * NHW;
    const float* w    = sel ? phw : thw;
    const float* bias = sel ? phb : thb;
    _Float16*   out   = (sel ? Kws : Qws) + (size_t)b * NHW * OD;
    const int n0 = nt * 64, o0 = ot * 64;

    __shared__ __align__(16) _Float16 Xs[64][72];   // [n][c], pad to 144B rows
    __shared__ __align__(16) _Float16 Ws[64][72];   // [o][c]

    const int t    = threadIdx.x;
    const int lane = t & 63, wave = t >> 6;
    const int l16  = lane & 15, lh = lane >> 4;

    f32x4 acc[4] = {};

    for (int c0 = 0; c0 < CIN; c0 += 64) {
        // stage Xs: transpose x[c][n] -> Xs[n][c] (f16)
        #pragma unroll
        for (int rep = 0; rep < 4; ++rep) {
            const int ci = rep * 16 + (t >> 4);
            const int nl = (t & 15) * 4;
            const float4 v = *(const float4*)&x[(size_t)(c0 + ci) * NHW + n0 + nl];
            Xs[nl + 0][ci] = (_Float16)v.x;
            Xs[nl + 1][ci] = (_Float16)v.y;
            Xs[nl + 2][ci] = (_Float16)v.z;
            Xs[nl + 3][ci] = (_Float16)v.w;
        }
        // stage Ws: w rows are c-contiguous already
        {
            const int oi = t >> 2;
            const int cl = (t & 3) * 16;
            const float4* wp = (const float4*)&w[(size_t)(o0 + oi) * CIN + c0 + cl];
            float4 a0 = wp[0], a1 = wp[1], a2 = wp[2], a3 = wp[3];
            *(f16x8*)&Ws[oi][cl]     = cvt8(a0, a1);
            *(f16x8*)&Ws[oi][cl + 8] = cvt8(a2, a3);
        }
        __syncthreads();

        #pragma unroll
        for (int kk = 0; kk < 2; ++kk) {
            const f16x8 afrag = *(const f16x8*)&Xs[wave * 16 + l16][kk * 32 + lh * 8];
            #pragma unroll
            for (int oo = 0; oo < 4; ++oo) {
                const f16x8 bfrag = *(const f16x8*)&Ws[oo * 16 + l16][kk * 32 + lh * 8];
                acc[oo] = MFMA16(afrag, bfrag, acc[oo]);
            }
        }
        __syncthreads();
    }

    #pragma unroll
    for (int oo = 0; oo < 4; ++oo) {
        const float bi = bias[o0 + oo * 16 + l16];
        #pragma unroll
        for (int r = 0; r < 4; ++r) {
            const int n = n0 + wave * 16 + lh * 4 + r;
            out[(size_t)n * OD + o0 + oo * 16 + l16] = (_Float16)(acc[oo][r] + bi);
        }
    }
}

// ---------------------------------------------------------------------------
// Fused flash attention:
//   S = Q K^T (per j-tile), logit = mask? S/4 : -2.5e8, online softmax,
//   O += P V, out[b][o][n] = O/L
// grid: 512 (b = bid&7 for XCD locality, qt = bid>>3), block 256 (4 waves x 16 q-rows)
// ---------------------------------------------------------------------------
__global__ __launch_bounds__(256)
void flash_attn(const _Float16* __restrict__ Qws, const _Float16* __restrict__ Kws,
                const float* __restrict__ emb, const float* __restrict__ mask,
                float* __restrict__ outp)
{
    const int bid = blockIdx.x;
    const int b = bid & 7, qt = bid >> 3;
    const int t = threadIdx.x, lane = t & 63, wave = t >> 6;
    const int l16 = lane & 15, lh = lane >> 4;

    __shared__ __align__(16) _Float16 Kl[64][264];    // [j][o]   33.8 KB
    __shared__ __align__(16) _Float16 Vl[256][72];    // [o][j]   36.9 KB
    __shared__ __align__(16) _Float16 Pl[4][16][72];  // per-wave [i][j] 9.2 KB

    const _Float16* Qb = Qws + (size_t)b * NHW * OD;
    const _Float16* Kb = Kws + (size_t)b * NHW * OD;
    const float*    Vb = emb + (size_t)b * OD * NHW;
    const float*    mb = mask + (size_t)b * NHW;

    // Q fragments for this wave's 16 rows, held for the whole kernel
    f16x8 qf[8];
    {
        const _Float16* qrow = Qb + (size_t)(qt * 64 + wave * 16 + l16) * OD + lh * 8;
        #pragma unroll
        for (int kk = 0; kk < 8; ++kk)
            qf[kk] = *(const f16x8*)(qrow + kk * 32);
    }

    f32x4 accO[16] = {};
    float M[4] = { -INFINITY, -INFINITY, -INFINITY, -INFINITY };
    float L[4] = { 0.f, 0.f, 0.f, 0.f };

    #pragma unroll 1
    for (int jt = 0; jt < 64; ++jt) {
        // ---- stage K tile: 64 x 256 f16, linear copy
        {
            const _Float16* src = Kb + (size_t)jt * 64 * OD;
            #pragma unroll
            for (int r = 0; r < 8; ++r) {
                const int p = r * 256 + t;
                const int row = p >> 5, cs = (p & 31) * 8;
                *(f16x8*)&Kl[row][cs] = *(const f16x8*)(src + row * OD + cs);
            }
        }
        // ---- stage V tile transposed-by-layout: Vl[o][j] from emb[b][o][jt*64+j] (f32->f16)
        {
            #pragma unroll
            for (int r = 0; r < 8; ++r) {
                const int p = r * 256 + t;
                const int o = p >> 3, j0 = (p & 7) * 8;
                const float4* vp = (const float4*)&Vb[(size_t)o * NHW + jt * 64 + j0];
                *(f16x8*)&Vl[o][j0] = cvt8(vp[0], vp[1]);
            }
        }
        __syncthreads();

        // ---- S = Q K^T : 16x64 per wave
        f32x4 S[4] = {};
        #pragma unroll
        for (int ct = 0; ct < 4; ++ct) {
            #pragma unroll
            for (int kk = 0; kk < 8; ++kk) {
                const f16x8 kf = *(const f16x8*)&Kl[ct * 16 + l16][kk * 32 + lh * 8];
                S[ct] = MFMA16(qf[kk], kf, S[ct]);
            }
        }

        // ---- mask + temperature
        float logit[4][4];
        #pragma unroll
        for (int ct = 0; ct < 4; ++ct) {
            const float mv = mb[jt * 64 + ct * 16 + l16];
            #pragma unroll
            for (int r = 0; r < 4; ++r)
                logit[ct][r] = (mv != 0.0f) ? S[ct][r] * 0.25f : -2.5e8f;
        }

        // ---- online softmax (rows 4*lh+r live on lane-group l16)
        float fac[4];
        #pragma unroll
        for (int r = 0; r < 4; ++r) {
            float tm = fmaxf(fmaxf(logit[0][r], logit[1][r]),
                             fmaxf(logit[2][r], logit[3][r]));
            tm = fmaxf(tm, __shfl_xor(tm, 1));
            tm = fmaxf(tm, __shfl_xor(tm, 2));
            tm = fmaxf(tm, __shfl_xor(tm, 4));
            tm = fmaxf(tm, __shfl_xor(tm, 8));
            const float nm = fmaxf(M[r], tm);
            fac[r] = __expf(M[r] - nm);
            M[r] = nm;
        }
        float rowsum[4] = { 0.f, 0.f, 0.f, 0.f };
        _Float16 ph[4][4];
        #pragma unroll
        for (int ct = 0; ct < 4; ++ct)
            #pragma unroll
            for (int r = 0; r < 4; ++r) {
                const float p = __expf(logit[ct][r] - M[r]);
                rowsum[r] += p;
                ph[ct][r] = (_Float16)p;
            }
        #pragma unroll
        for (int r = 0; r < 4; ++r) {
            float s = rowsum[r];
            s += __shfl_xor(s, 1);
            s += __shfl_xor(s, 2);
            s += __shfl_xor(s, 4);
            s += __shfl_xor(s, 8);
            L[r] = L[r] * fac[r] + s;
        }
        #pragma unroll
        for (int oo = 0; oo < 16; ++oo)
            #pragma unroll
            for (int r = 0; r < 4; ++r)
                accO[oo][r] *= fac[r];

        // ---- P -> LDS (re-fragment for PV)
        #pragma unroll
        for (int ct = 0; ct < 4; ++ct)
            #pragma unroll
            for (int r = 0; r < 4; ++r)
                Pl[wave][lh * 4 + r][ct * 16 + l16] = ph[ct][r];
        __syncthreads();

        // ---- O += P V
        f16x8 pf[2];
        #pragma unroll
        for (int kc = 0; kc < 2; ++kc)
            pf[kc] = *(const f16x8*)&Pl[wave][l16][kc * 32 + lh * 8];
        #pragma unroll
        for (int oo = 0; oo < 16; ++oo) {
            #pragma unroll
            for (int kc = 0; kc < 2; ++kc) {
                const f16x8 vf = *(const f16x8*)&Vl[oo * 16 + l16][kc * 32 + lh * 8];
                accO[oo] = MFMA16(pf[kc], vf, accO[oo]);
            }
        }
        __syncthreads();
    }

    // ---- epilogue: divide by row sums, write out[b][o][n] (f32)
    float rl[4];
    #pragma unroll
    for (int r = 0; r < 4; ++r) rl[r] = 1.0f / L[r];
    #pragma unroll
    for (int oo = 0; oo < 16; ++oo) {
        const int o = oo * 16 + l16;
        #pragma unroll
        for (int r = 0; r < 4; ++r) {
            const int n = qt * 64 + wave * 16 + lh * 4 + r;
            outp[((size_t)b * OD + o) * NHW + n] = accO[oo][r] * rl[r];
        }
    }
}

extern "C" void kernel_launch(void* const* d_in, const int* in_sizes, int n_in,
                              void* d_out, int out_size, void* d_ws, size_t ws_size,
                              hipStream_t stream) {
    const float* xq   = (const float*)d_in[0];
    const float* xs   = (const float*)d_in[1];
    const float* emb  = (const float*)d_in[2];
    const float* mask = (const float*)d_in[3];
    const float* thw  = (const float*)d_in[4];
    const float* thb  = (const float*)d_in[5];
    const float* phw  = (const float*)d_in[6];
    const float* phb  = (const float*)d_in[7];
    float* out = (float*)d_out;

    _Float16* Qws = (_Float16*)d_ws;
    _Float16* Kws = (_Float16*)((char*)d_ws + (size_t)BN * NHW * OD * sizeof(_Float16));

    prep_gemm<<<dim3(64, 4, 16), 256, 0, stream>>>(xq, xs, thw, thb, phw, phb, Qws, Kws);
    flash_attn<<<dim3(512), 256, 0, stream>>>(Qws, Kws, emb, mask, out);
}